// Round 8
// baseline (7656.475 us; speedup 1.0000x reference)
//
#include <hip/hip_runtime.h>
#include <math.h>

#define EOS_TOK 1
#define SOS_TOK 2

#define Bn 32
#define Hn 512
#define En 256
#define Vn 32000
#define G3H 1536                 // 3*H
#define NROWS (Vn + G3H)         // 33536 = 256*131
#define NBLK 256                 // 1 block/CU
#define NTHR 1024                // 16 waves
#define RPB 131                  // rows per block
#define TILE_R 16                // rows per LDS tile (32 KB)
#define NTILE 9                  // ceil(131/16) -> padded 144 rows
#define GHPB 6                   // gh rows per block in pre-pass

typedef unsigned long long ull;

// ---- relaxed agent-scope (device-coherent, no cache-maintenance) accessors ----
template <typename T>
__device__ __forceinline__ T ldA(const T* p) {
    return __hip_atomic_load(p, __ATOMIC_RELAXED, __HIP_MEMORY_SCOPE_AGENT);
}
template <typename T>
__device__ __forceinline__ void stA(T* p, T v) {
    __hip_atomic_store(p, v, __ATOMIC_RELAXED, __HIP_MEMORY_SCOPE_AGENT);
}

// ---- workspace layout ----
// [0,192K): gh  [192K,196K): slots  [196K..): done  [256K..): 65 rotating h buffers (64KB each)
struct WS { float* gh; ull* slots; int* done; float* hb; };
__device__ __forceinline__ WS get_ws(void* ws) {
    WS w;
    w.gh    = (float*)ws;
    w.slots = (ull*)((char*)ws + 196608);
    w.done  = (int*)((char*)ws + 196608 + 4096);
    w.hb    = (float*)((char*)ws + 262144);
    return w;
}
#define HBUF(w, k) ((w).hb + (size_t)(k) * (Bn * Hn))
// tiled h layout: float index of h[b][col] = (col>>2)*128 + b*4 + (col&3)
__device__ __forceinline__ int h_idx(int b, int col) {
    return ((col >> 2) << 7) + (b << 2) + (col & 3);
}

// ---- fence-free grid barrier: 32 leaf counters (8 blocks each) + release word ----
struct PadCnt { ull v; ull pad[7]; };
__device__ PadCnt g_leaf[32];
__device__ ull    g_release;

__device__ __forceinline__ void grid_barrier(int bid) {
    __syncthreads();
    if (threadIdx.x == 0) {
        __builtin_amdgcn_s_waitcnt(0);
        ull my = __hip_atomic_fetch_add(&g_leaf[bid >> 3].v, 1ull,
                                        __ATOMIC_RELAXED, __HIP_MEMORY_SCOPE_AGENT) + 1;
        ull k = (my + 7) >> 3;
        if (bid == 0) {
            ull need = k << 3;
            for (;;) {
                bool again = false;
                #pragma unroll
                for (int i = 0; i < 32; ++i)
                    again |= (ldA(&g_leaf[i].v) < need);
                if (!again) break;
                __builtin_amdgcn_s_sleep(1);
            }
            stA(&g_release, k);
        } else {
            while (ldA(&g_release) < k) __builtin_amdgcn_s_sleep(2);
        }
        __asm__ __volatile__("" ::: "memory");
    }
    __syncthreads();
}

__device__ __forceinline__ unsigned int fkey(float f) {
    unsigned int b = __float_as_uint(f);
    return (b & 0x80000000u) ? ~b : (b | 0x80000000u);
}

// ---- async DMA: wave wv stages tile-row wv (2 KB) as 2 x 1KB global_load_lds ----
__device__ __forceinline__ void issue_tile(
    int i, char* tbuf, int rs, int wv, int lane,
    const float* __restrict__ W_proj, const float* __restrict__ W_hh)
{
    int rl = i * TILE_R + wv;
    int r = rs + rl;
    if (rl >= RPB) r = 0;                    // pad rows: safe dummy, skipped in compute
    const float* base = (r < Vn) ? (W_proj + (size_t)r * Hn)
                                 : (W_hh   + (size_t)(r - Vn) * Hn);
    const float* g0 = base + lane * 4;
    const float* g1 = base + 256 + lane * 4;
    char* l0 = tbuf + wv * 2048;
    char* l1 = l0 + 1024;
    __builtin_amdgcn_global_load_lds((const __attribute__((address_space(1))) void*)g0,
                                     (__attribute__((address_space(3))) void*)l0, 16, 0, 0);
    __builtin_amdgcn_global_load_lds((const __attribute__((address_space(1))) void*)g1,
                                     (__attribute__((address_space(3))) void*)l1, 16, 0, 0);
}

// ---------------- Phase B: DMA-pipelined logits + gh, partial argmax ----------------
__device__ __forceinline__ void phase_b(
    int tid, int bid, int t,
    const float* __restrict__ W_proj, const float* __restrict__ W_hh,
    const float* __restrict__ b_proj, const float* __restrict__ b_hh,
    const float* __restrict__ hcur, float* __restrict__ ws_gh,
    ull* __restrict__ slots, char* smem)
{
    const int lane = tid & 63, wv = tid >> 6;
    const int g = tid >> 5, b = tid & 31;
    const int row16 = g & 15, kh = g >> 4;
    const int rs = bid * RPB;
    char* tb0 = smem;
    char* tb1 = smem + 32768;

    issue_tile(0, tb0, rs, wv, lane, W_proj, W_hh);
    issue_tile(1, tb1, rs, wv, lane, W_proj, W_hh);

    float accs[NTILE];
    const float4* hb = ((const float4*)hcur) + (size_t)(kh * 64) * 32 + b;

    for (int i = 0; i < NTILE; ++i) {
        if (i < NTILE - 1) asm volatile("s_waitcnt vmcnt(2)" ::: "memory");
        else               asm volatile("s_waitcnt vmcnt(0)" ::: "memory");
        asm volatile("s_barrier" ::: "memory");          // tile i fully landed, grid-wide in block
        const float4* tl = (const float4*)(((i & 1) ? tb1 : tb0) + row16 * 2048 + kh * 1024);
        float a0 = 0.f, a1 = 0.f;
        #pragma unroll 4
        for (int e = 0; e < 64; ++e) {
            float4 w4 = tl[e];                            // LDS broadcast read
            float4 h4 = hb[(size_t)e * 32];               // L2-hot cached global
            a0 = fmaf(h4.x, w4.x, a0);
            a1 = fmaf(h4.y, w4.y, a1);
            a0 = fmaf(h4.z, w4.z, a0);
            a1 = fmaf(h4.w, w4.w, a1);
        }
        accs[i] = a0 + a1;
        asm volatile("s_barrier" ::: "memory");          // all reads of this buf done
        if (i + 2 < NTILE) issue_tile(i + 2, (i & 1) ? tb1 : tb0, rs, wv, lane, W_proj, W_hh);
    }

    // combine K-halves via LDS scratch (tiles dead now), then argmax/gh
    float* scratch = (float*)smem;                       // 144*32 floats = 18 KB
    ull* red = (ull*)(smem + 32768);                     // 16*32 ull = 4 KB
    if (kh == 1) {
        #pragma unroll
        for (int i = 0; i < NTILE; ++i)
            scratch[(i * TILE_R + row16) * Bn + b] = accs[i];
    }
    __syncthreads();
    if (kh == 0) {
        ull best = 0ull;
        #pragma unroll
        for (int i = 0; i < NTILE; ++i) {
            int rl = i * TILE_R + row16;
            if (rl < RPB) {
                int r = rs + rl;
                float tot = accs[i] + scratch[rl * Bn + b];
                if (r < Vn) {
                    float v = tot + b_proj[r];
                    ull pk = ((ull)fkey(v) << 32) | (unsigned int)(~(unsigned int)r);
                    if (pk > best) best = pk;            // ties: smaller r wins via ~r
                } else {
                    stA(&ws_gh[(size_t)b * G3H + (r - Vn)], tot + b_hh[r - Vn]);
                }
            }
        }
        red[(row16 << 5) + b] = best;
    }
    __syncthreads();
    if (tid < Bn) {
        ull m = red[tid];
        #pragma unroll
        for (int s = 1; s < 16; ++s) {
            ull v = red[(s << 5) + tid];
            if (v > m) m = v;
        }
        if (m != 0ull)
            atomicMax(&slots[((size_t)(t & 1) * 8 + (bid & 7)) * Bn + tid], m);
    }
}

// ---------------- pre-pass: gh(h0) only (6 rows/block), plain loads ----------------
__device__ __forceinline__ void phase_b_pre(
    int tid, int bid,
    const float* __restrict__ W_hh, const float* __restrict__ b_hh,
    const float* __restrict__ h0, float* __restrict__ ws_gh, char* smem)
{
    const int g = tid >> 5, b = tid & 31;
    const int row6 = g >> 1, kh = g & 1;
    const bool act = g < 12;
    float* scratch = (float*)smem;                       // 6*32 floats
    float a = 0.f;
    int rglob = bid * GHPB + row6;                       // 0..1535
    if (act) {
        const float4* wr = (const float4*)(W_hh + (size_t)rglob * Hn) + kh * 64;
        const float4* hb = ((const float4*)h0) + (size_t)(kh * 64) * 32 + b;
        float a0 = 0.f, a1 = 0.f;
        #pragma unroll 4
        for (int e = 0; e < 64; ++e) {
            float4 w4 = wr[e];
            float4 h4 = hb[(size_t)e * 32];
            a0 = fmaf(h4.x, w4.x, a0);
            a1 = fmaf(h4.y, w4.y, a1);
            a0 = fmaf(h4.z, w4.z, a0);
            a1 = fmaf(h4.w, w4.w, a1);
        }
        a = a0 + a1;
    }
    if (act && kh == 1) scratch[row6 * Bn + b] = a;
    __syncthreads();
    if (act && kh == 0)
        stA(&ws_gh[(size_t)b * G3H + rglob], a + scratch[row6 * Bn + b] + b_hh[rglob]);
}

// ---------------- Phase A: token resolve + embed/gx + gate combine + h update -------
__device__ __forceinline__ void phase_a(
    int tid, int bid, int t, int T,
    const float* __restrict__ emb, const float* __restrict__ W_ih,
    const float* __restrict__ b_ih,
    const float* __restrict__ hold_, float* __restrict__ hnew,
    const float* __restrict__ ws_gh,
    ull* __restrict__ slots, int* __restrict__ done,
    int* __restrict__ out, char* smem)
{
    int* s_tok = (int*)smem;                             // 32 ints
    float* s_gx = (float*)(smem + 128);                  // [2][3][32] floats

    if (tid < Bn) {
        int b = tid;
        int tok, dnew;
        if (t == 0) { tok = SOS_TOK; dnew = 0; }
        else {
            const ull* sl = slots + (size_t)((t - 1) & 1) * (8 * Bn);
            ull m = ldA(&sl[b]);
            #pragma unroll
            for (int s = 1; s < 8; ++s) {
                ull v = ldA(&sl[s * Bn + b]);
                if (v > m) m = v;
            }
            int idx = (int)(~(unsigned int)m);
            int dold = ldA(&done[((t - 1) & 1) * Bn + b]);
            tok  = dold ? EOS_TOK : idx;
            dnew = dold | (idx == EOS_TOK);
        }
        s_tok[b] = tok;
        if (bid == 0) {
            stA(&done[(t & 1) * Bn + b], dnew);
            if (t > 0) out[(size_t)(t - 1) * Bn + b] = tok;
            ull* sr = slots + (size_t)(t & 1) * (8 * Bn);
            #pragma unroll
            for (int s = 0; s < 8; ++s) stA(&sr[s * Bn + b], 0ull);
        }
    }
    __syncthreads();
    if (t >= T) return;

    // gx dots: block bid owns columns {bid, bid+256}; 192 dots of length E,
    // 4 threads per dot -> 768 active threads.
    if (tid < 768) {
        int d    = tid >> 2;
        int q    = tid & 3;
        int b    = d & 31;
        int rem  = d >> 5;
        int gate = rem >> 1;
        int ci   = rem & 1;
        int col  = bid + (ci << 8);
        const float* wrow = W_ih + (size_t)(gate * Hn + col) * En + q * (En / 4);
        const float* xrow = emb + (size_t)s_tok[b] * En + q * (En / 4);
        float ax = 0.f, ay = 0.f;
        #pragma unroll
        for (int e4 = 0; e4 < En / 16; ++e4) {
            float4 w4 = *(const float4*)(wrow + 4 * e4);
            float4 x4 = *(const float4*)(xrow + 4 * e4);
            ax = fmaf(x4.x, w4.x, ax);
            ay = fmaf(x4.y, w4.y, ay);
            ax = fmaf(x4.z, w4.z, ax);
            ay = fmaf(x4.w, w4.w, ay);
        }
        float a = ax + ay;
        a += __shfl_xor(a, 1);
        a += __shfl_xor(a, 2);
        if (q == 0) s_gx[(ci * 3 + gate) * Bn + b] = a;
    }
    __syncthreads();

    if (tid < 64) {
        int b   = tid & 31;
        int ci  = tid >> 5;
        int col = bid + (ci << 8);
        float gxr = s_gx[(ci * 3 + 0) * Bn + b] + b_ih[col];
        float gxz = s_gx[(ci * 3 + 1) * Bn + b] + b_ih[Hn + col];
        float gxn = s_gx[(ci * 3 + 2) * Bn + b] + b_ih[2 * Hn + col];
        const float* ghrow = ws_gh + (size_t)b * G3H;    // includes b_hh already
        float ghr = ldA(&ghrow[col]);
        float ghz = ldA(&ghrow[Hn + col]);
        float ghn = ldA(&ghrow[2 * Hn + col]);
        float r = 1.0f / (1.0f + expf(-(gxr + ghr)));
        float z = 1.0f / (1.0f + expf(-(gxz + ghz)));
        float n = tanhf(gxn + r * ghn);
        int ti = h_idx(b, col);
        float hold = hold_[ti];                          // plain (write-once buffer)
        stA(&hnew[ti], (1.0f - z) * n + z * hold);
    }
}

// ================= cooperative single-kernel path =================
__global__ void __launch_bounds__(NTHR, 4)
decode_coop(const float* __restrict__ hidden, const float* __restrict__ emb,
            const float* __restrict__ W_ih, const float* __restrict__ W_hh,
            const float* __restrict__ b_ih, const float* __restrict__ b_hh,
            const float* __restrict__ W_proj, const float* __restrict__ b_proj,
            const int* __restrict__ max_len_p, int* __restrict__ out, void* ws_raw)
{
    const int tid = threadIdx.x, bid = blockIdx.x;
    __shared__ char smem[65536];
    WS w = get_ws(ws_raw);
    const int T = max_len_p[0];

    // init: hidden (B,H) -> hbuf[0] in tiled layout
    for (int i = bid * NTHR + tid; i < Bn * Hn; i += NBLK * NTHR) {
        int b = i >> 9, col = i & (Hn - 1);
        stA(HBUF(w, 0) + h_idx(b, col), hidden[i]);
    }
    grid_barrier(bid);

    phase_b_pre(tid, bid, W_hh, b_hh, HBUF(w, 0), w.gh, smem);
    grid_barrier(bid);

    for (int t = 0; t < T; ++t) {
        phase_a(tid, bid, t, T, emb, W_ih, b_ih, HBUF(w, t), HBUF(w, t + 1),
                w.gh, w.slots, w.done, out, smem);
        grid_barrier(bid);
        phase_b(tid, bid, t, W_proj, W_hh, b_proj, b_hh, HBUF(w, t + 1),
                w.gh, w.slots, smem);
        grid_barrier(bid);
    }
    phase_a(tid, bid, T, T, emb, W_ih, b_ih, HBUF(w, T), HBUF(w, 64),
            w.gh, w.slots, w.done, out, smem);
}

// ================= non-cooperative fallback path =================
__global__ void __launch_bounds__(NTHR)
k_init(const float* __restrict__ hidden, void* ws_raw) {
    WS w = get_ws(ws_raw);
    int i = blockIdx.x * NTHR + threadIdx.x;
    if (i < Bn * Hn) {
        int b = i >> 9, col = i & (Hn - 1);
        stA(HBUF(w, 0) + h_idx(b, col), hidden[i]);
    }
}

__global__ void __launch_bounds__(NTHR, 4)
k_pre(const float* __restrict__ W_hh, const float* __restrict__ b_hh, void* ws_raw) {
    __shared__ char smem[65536];
    WS w = get_ws(ws_raw);
    phase_b_pre(threadIdx.x, blockIdx.x, W_hh, b_hh, HBUF(w, 0), w.gh, smem);
}

__global__ void __launch_bounds__(NTHR, 4)
k_b(int t, const int* __restrict__ max_len_p,
    const float* __restrict__ W_proj, const float* __restrict__ W_hh,
    const float* __restrict__ b_proj, const float* __restrict__ b_hh, void* ws_raw)
{
    if (t >= max_len_p[0]) return;
    __shared__ char smem[65536];
    WS w = get_ws(ws_raw);
    phase_b(threadIdx.x, blockIdx.x, t, W_proj, W_hh, b_proj, b_hh,
            HBUF(w, t + 1), w.gh, w.slots, smem);
}

__global__ void __launch_bounds__(NTHR, 4)
k_a(int t, const int* __restrict__ max_len_p,
    const float* __restrict__ emb, const float* __restrict__ W_ih,
    const float* __restrict__ b_ih, int* __restrict__ out, void* ws_raw)
{
    int T = max_len_p[0];
    if (t > T) return;
    __shared__ char smem[65536];
    WS w = get_ws(ws_raw);
    int tn = (t < 64) ? (t + 1) : 64;
    phase_a(threadIdx.x, blockIdx.x, t, T, emb, W_ih, b_ih,
            HBUF(w, t), HBUF(w, tn), w.gh, w.slots, w.done, out, smem);
}

extern "C" void kernel_launch(void* const* d_in, const int* in_sizes, int n_in,
                              void* d_out, int out_size, void* d_ws, size_t ws_size,
                              hipStream_t stream) {
    const float* hidden = (const float*)d_in[0];
    const float* emb    = (const float*)d_in[1];
    const float* W_ih   = (const float*)d_in[2];
    const float* W_hh   = (const float*)d_in[3];
    const float* b_ih   = (const float*)d_in[4];
    const float* b_hh   = (const float*)d_in[5];
    const float* W_proj = (const float*)d_in[6];
    const float* b_proj = (const float*)d_in[7];
    const int* max_len  = (const int*)d_in[8];
    int* out = (int*)d_out;
    void* ws = d_ws;

    void* args[] = {&hidden, &emb, &W_ih, &W_hh, &b_ih, &b_hh,
                    &W_proj, &b_proj, &max_len, &out, &ws};
    hipError_t err = hipLaunchCooperativeKernel((const void*)decode_coop,
                                                dim3(NBLK), dim3(NTHR), args, 0, stream);
    if (err != hipSuccess) {
        (void)hipGetLastError();   // clear sticky error; deterministic fallback
        hipLaunchKernelGGL(k_init, dim3(16), dim3(NTHR), 0, stream, hidden, ws);
        hipLaunchKernelGGL(k_pre, dim3(NBLK), dim3(NTHR), 0, stream, W_hh, b_hh, ws);
        for (int t = 0; t <= 64; ++t) {
            hipLaunchKernelGGL(k_a, dim3(NBLK), dim3(NTHR), 0, stream,
                               t, max_len, emb, W_ih, b_ih, out, ws);
            if (t < 64)
                hipLaunchKernelGGL(k_b, dim3(NBLK), dim3(NTHR), 0, stream,
                                   t, max_len, W_proj, W_hh, b_proj, b_hh, ws);
        }
    }
}